// Round 3
// baseline (685.937 us; speedup 1.0000x reference)
//
#include <hip/hip_runtime.h>

// Local cost-volume correlation, fp32 vector path, DPP window sharing.
// out[b, dy*9+dx, h, w] = (1/256) sum_c in1[b,c,h,w] * in2[b,c,h+dy-4,w+dx-4]
//
// R6 design (from R5 post-mortem: float4 STAGING ARRAYS were demoted to
// scratch — WRITE_SIZE 31->815 MB, FETCH 143->421 MB, VGPR_Count 64,
// VALUBusy 16%. The ping-pong schedule itself was never register-resident):
//  - same schedule as R5: ping-pong double buffer of 4-channel groups,
//    8 float4 loads in flight per buffer (16 steady-state) so each wave
//    self-hides load latency under ~400 VALU cycles of FMA+DPP
//  - staging is now 16 individually NAMED float4 variables (a0..a3/m0..m3,
//    b0..b3/n0..n3) — no aggregate the compiler can demote to local mem
//  - live regs ~= 64 staging + 36 acc + ~15 addr/temps ~= 115 < 128
//    (launch_bounds(256,4) VGPR cap), so no spill either
//  - w[12]/acc[4][9] arrays keep fully-static unrolled indexing (R4-proven:
//    VGPR 44, zero scratch)

#define CH 256
#define HH 96
#define WW 128
#define CS (HH * WW)
#define CS4 (CS / 4)   // float4s per channel plane = 3072

__device__ __forceinline__ float wshr1(float x) {  // lane i <- lane i-1
  union { float f; int i; } u, o;
  u.f = x;
  o.i = __builtin_amdgcn_update_dpp(0, u.i, 0x138, 0xF, 0xF, true);
  return o.f;
}
__device__ __forceinline__ float wshl1(float x) {  // lane i <- lane i+1
  union { float f; int i; } u, o;
  u.f = x;
  o.i = __builtin_amdgcn_update_dpp(0, u.i, 0x130, 0xF, 0xF, true);
  return o.f;
}

// consume one channel: DPP window + 36 FMAs (static-index arrays only)
__device__ __forceinline__ void comp1(float (&acc)[4][9], const float4 a4,
                                      const float4 m4) {
  float w[12];
  w[0] = wshr1(m4.x); w[1] = wshr1(m4.y); w[2] = wshr1(m4.z); w[3] = wshr1(m4.w);
  w[4] = m4.x; w[5] = m4.y; w[6] = m4.z; w[7] = m4.w;
  w[8] = wshl1(m4.x); w[9] = wshl1(m4.y); w[10] = wshl1(m4.z); w[11] = wshl1(m4.w);
  const float av[4] = {a4.x, a4.y, a4.z, a4.w};
#pragma unroll
  for (int p = 0; p < 4; ++p)
#pragma unroll
    for (int d = 0; d < 9; ++d)
      acc[p][d] = fmaf(av[p], w[p + d], acc[p][d]);
}

// load one 4-channel group into 8 named float4 regs, advance pointers
#define LOAD_A                                                        \
  do {                                                                \
    a0 = q1[0]; a1 = q1[CS4]; a2 = q1[2 * CS4]; a3 = q1[3 * CS4];     \
    m0 = q2[0]; m1 = q2[CS4]; m2 = q2[2 * CS4]; m3 = q2[3 * CS4];     \
    q1 += 4 * CS4; q2 += 4 * CS4;                                     \
  } while (0)
#define LOAD_B                                                        \
  do {                                                                \
    b0 = q1[0]; b1 = q1[CS4]; b2 = q1[2 * CS4]; b3 = q1[3 * CS4];     \
    n0 = q2[0]; n1 = q2[CS4]; n2 = q2[2 * CS4]; n3 = q2[3 * CS4];     \
    q1 += 4 * CS4; q2 += 4 * CS4;                                     \
  } while (0)
#define COMP_A                                                        \
  do { comp1(acc, a0, m0); comp1(acc, a1, m1);                        \
       comp1(acc, a2, m2); comp1(acc, a3, m3); } while (0)
#define COMP_B                                                        \
  do { comp1(acc, b0, n0); comp1(acc, b1, n1);                        \
       comp1(acc, b2, n2); comp1(acc, b3, n3); } while (0)

__global__ __launch_bounds__(256, 4) void corr_dpp(
    const float* __restrict__ in1, const float* __restrict__ in2,
    float* __restrict__ out)
{
  // ---- block decode, XCD-swizzled: tile's 9 dy-blocks share blockIdx%8 ----
  const int j    = blockIdx.x;          // grid = 864
  const int xcd  = j & 7;
  const int s    = j >> 3;              // 0..107
  const int dy   = s % 9;
  const int tq   = s / 9;               // 0..11
  const int tile = tq * 8 + xcd;        // 0..95
  const int band = tile % 12;
  const int b    = tile / 12;
  const int dyo  = dy - 4;

  // ---- thread decode: 4 waves x (2 rows x 32 col-groups), 4 px/lane ----
  const int tid  = threadIdx.x;
  const int wv   = tid >> 6;
  const int lane = tid & 63;
  const int r    = lane >> 5;
  const int g    = lane & 31;
  const int h    = band * 8 + wv * 2 + r;   // 0..95, always valid
  const int px   = g << 2;                  // 0..124
  const int r2   = h + dyo;                 // in2 row, may be OOB
  const bool rowok = (unsigned)r2 < (unsigned)HH;
  const int r2c  = r2 < 0 ? 0 : (r2 > HH - 1 ? HH - 1 : r2);

  const float4* __restrict__ q1 =
      (const float4*)(in1 + ((size_t)b * CH * HH + h)   * WW + px);
  const float4* __restrict__ q2 =
      (const float4*)(in2 + ((size_t)b * CH * HH + r2c) * WW + px);

  float acc[4][9];
#pragma unroll
  for (int p = 0; p < 4; ++p)
#pragma unroll
    for (int d = 0; d < 9; ++d) acc[p][d] = 0.f;

  float4 a0, a1, a2, a3, m0, m1, m2, m3;   // group A (named: no demotion)
  float4 b0, b1, b2, b3, n0, n1, n2, n3;   // group B

  // ---- ping-pong double-buffered channel loop: 64 groups of 4 channels ----
  LOAD_A;                              // group 0
#pragma unroll 1
  for (int cc = 0; cc < CH - 8; cc += 8) {
    LOAD_B;                            // group 2i+1
    COMP_A;                            // group 2i
    LOAD_A;                            // group 2i+2
    COMP_B;                            // group 2i+1
  }
  LOAD_B;                              // group 63 (c = 252..255)
  COMP_A;                              // group 62
  COMP_B;                              // group 63

  // ---- epilogue: zero OOB (row + col) contributions, scale, float4 store ----
  const float sc = 1.0f / (float)CH;
  float* po = out + (((size_t)b * 81 + dy * 9) * HH + h) * WW + px;
#pragma unroll
  for (int d = 0; d < 9; ++d) {
    float v[4];
#pragma unroll
    for (int p = 0; p < 4; ++p) {
      const int col2 = px + p + d - 4;                       // in2 column
      const bool ok  = rowok && ((unsigned)col2 < (unsigned)WW);
      v[p] = ok ? acc[p][d] * sc : 0.f;
    }
    *(float4*)po = make_float4(v[0], v[1], v[2], v[3]);
    po += (size_t)CS;  // next (dy,dx) plane
  }
}

extern "C" void kernel_launch(void* const* d_in, const int* in_sizes, int n_in,
                              void* d_out, int out_size, void* d_ws, size_t ws_size,
                              hipStream_t stream) {
  const float* in1 = (const float*)d_in[0];
  const float* in2 = (const float*)d_in[1];
  float* out = (float*)d_out;
  hipLaunchKernelGGL(corr_dpp, dim3(864), dim3(256), 0, stream, in1, in2, out);
}

// Round 4
// 324.485 us; speedup vs baseline: 2.1139x; 2.1139x over previous
//
#include <hip/hip_runtime.h>

// Local cost-volume correlation, fp32 vector path, DPP window sharing.
// out[b, dy*9+dx, h, w] = (1/256) sum_c in1[b,c,h,w] * in2[b,c,h+dy-4,w+dx-4]
//
// R7 design (from R5/R6 post-mortem: 4-channel ping-pong needs ~140 live
// VGPRs > the 128 cap of launch_bounds(256,4); allocator responded by
// clamping to 64 and streaming staging through scratch — WRITE_SIZE ~1 GB).
//  - SHALLOWER pipeline that FITS: 2-channel-group ping-pong, 8 named
//    float4 staging regs (32 VGPR). Peak live ~= 32 + 36 acc + 12 window
//    + ~15 addr ~= 95 < 128 -> clean alloc, 4 waves/SIMD still allowed.
//  - still 2x R4's loads-in-flight (8 vs 4), issued one compute-group
//    (~200 VALU cyc) ahead of use; TLP (3.4 waves/SIMD) covers the rest.
//  - VGPR > 128 is NOT an option: HW wave steps are 8/4/2 per SIMD, so
//    >128 regs => 2 waves/SIMD < grid-limited 3.4 -> net loss. Stay under.
//  - everything else identical to R4 (proven): wave = 2 rows x 32 groups
//    x 4 px, DPP wave_shr/shl window, branch-free OOB zeroing at store,
//    XCD-swizzled dy-blocks.

#define CH 256
#define HH 96
#define WW 128
#define CS (HH * WW)
#define CS4 (CS / 4)   // float4s per channel plane = 3072

__device__ __forceinline__ float wshr1(float x) {  // lane i <- lane i-1
  union { float f; int i; } u, o;
  u.f = x;
  o.i = __builtin_amdgcn_update_dpp(0, u.i, 0x138, 0xF, 0xF, true);
  return o.f;
}
__device__ __forceinline__ float wshl1(float x) {  // lane i <- lane i+1
  union { float f; int i; } u, o;
  u.f = x;
  o.i = __builtin_amdgcn_update_dpp(0, u.i, 0x130, 0xF, 0xF, true);
  return o.f;
}

// consume one channel: DPP window + 36 FMAs (static-index arrays only)
__device__ __forceinline__ void comp1(float (&acc)[4][9], const float4 a4,
                                      const float4 m4) {
  float w[12];
  w[0] = wshr1(m4.x); w[1] = wshr1(m4.y); w[2] = wshr1(m4.z); w[3] = wshr1(m4.w);
  w[4] = m4.x; w[5] = m4.y; w[6] = m4.z; w[7] = m4.w;
  w[8] = wshl1(m4.x); w[9] = wshl1(m4.y); w[10] = wshl1(m4.z); w[11] = wshl1(m4.w);
  const float av[4] = {a4.x, a4.y, a4.z, a4.w};
#pragma unroll
  for (int p = 0; p < 4; ++p)
#pragma unroll
    for (int d = 0; d < 9; ++d)
      acc[p][d] = fmaf(av[p], w[p + d], acc[p][d]);
}

// load one 2-channel group into 4 named float4 regs, advance pointers
#define LOAD_A                                                \
  do {                                                        \
    a0 = q1[0]; a1 = q1[CS4];                                 \
    m0 = q2[0]; m1 = q2[CS4];                                 \
    q1 += 2 * CS4; q2 += 2 * CS4;                             \
  } while (0)
#define LOAD_B                                                \
  do {                                                        \
    b0 = q1[0]; b1 = q1[CS4];                                 \
    n0 = q2[0]; n1 = q2[CS4];                                 \
    q1 += 2 * CS4; q2 += 2 * CS4;                             \
  } while (0)
#define COMP_A  do { comp1(acc, a0, m0); comp1(acc, a1, m1); } while (0)
#define COMP_B  do { comp1(acc, b0, n0); comp1(acc, b1, n1); } while (0)

__global__ __launch_bounds__(256, 4) void corr_dpp(
    const float* __restrict__ in1, const float* __restrict__ in2,
    float* __restrict__ out)
{
  // ---- block decode, XCD-swizzled: tile's 9 dy-blocks share blockIdx%8 ----
  const int j    = blockIdx.x;          // grid = 864
  const int xcd  = j & 7;
  const int s    = j >> 3;              // 0..107
  const int dy   = s % 9;
  const int tq   = s / 9;               // 0..11
  const int tile = tq * 8 + xcd;        // 0..95
  const int band = tile % 12;
  const int b    = tile / 12;
  const int dyo  = dy - 4;

  // ---- thread decode: 4 waves x (2 rows x 32 col-groups), 4 px/lane ----
  const int tid  = threadIdx.x;
  const int wv   = tid >> 6;
  const int lane = tid & 63;
  const int r    = lane >> 5;
  const int g    = lane & 31;
  const int h    = band * 8 + wv * 2 + r;   // 0..95, always valid
  const int px   = g << 2;                  // 0..124
  const int r2   = h + dyo;                 // in2 row, may be OOB
  const bool rowok = (unsigned)r2 < (unsigned)HH;
  const int r2c  = r2 < 0 ? 0 : (r2 > HH - 1 ? HH - 1 : r2);

  const float4* __restrict__ q1 =
      (const float4*)(in1 + ((size_t)b * CH * HH + h)   * WW + px);
  const float4* __restrict__ q2 =
      (const float4*)(in2 + ((size_t)b * CH * HH + r2c) * WW + px);

  float acc[4][9];
#pragma unroll
  for (int p = 0; p < 4; ++p)
#pragma unroll
    for (int d = 0; d < 9; ++d) acc[p][d] = 0.f;

  float4 a0, a1, m0, m1;   // group A staging (named scalars, 16 VGPR)
  float4 b0, b1, n0, n1;   // group B staging

  // ---- ping-pong double-buffered channel loop: 128 groups of 2 channels ----
  LOAD_A;                              // group 0
#pragma unroll 1
  for (int cc = 0; cc < CH - 4; cc += 4) {   // 63 iterations
    LOAD_B;                            // group 2i+1
    COMP_A;                            // group 2i
    LOAD_A;                            // group 2i+2
    COMP_B;                            // group 2i+1
  }
  LOAD_B;                              // group 127 (c = 254,255)
  COMP_A;                              // group 126
  COMP_B;                              // group 127

  // ---- epilogue: zero OOB (row + col) contributions, scale, float4 store ----
  const float sc = 1.0f / (float)CH;
  float* po = out + (((size_t)b * 81 + dy * 9) * HH + h) * WW + px;
#pragma unroll
  for (int d = 0; d < 9; ++d) {
    float v[4];
#pragma unroll
    for (int p = 0; p < 4; ++p) {
      const int col2 = px + p + d - 4;                       // in2 column
      const bool ok  = rowok && ((unsigned)col2 < (unsigned)WW);
      v[p] = ok ? acc[p][d] * sc : 0.f;
    }
    *(float4*)po = make_float4(v[0], v[1], v[2], v[3]);
    po += (size_t)CS;  // next (dy,dx) plane
  }
}

extern "C" void kernel_launch(void* const* d_in, const int* in_sizes, int n_in,
                              void* d_out, int out_size, void* d_ws, size_t ws_size,
                              hipStream_t stream) {
  const float* in1 = (const float*)d_in[0];
  const float* in2 = (const float*)d_in[1];
  float* out = (float*)d_out;
  hipLaunchKernelGGL(corr_dpp, dim3(864), dim3(256), 0, stream, in1, in2, out);
}

// Round 5
// 302.126 us; speedup vs baseline: 2.2704x; 1.0740x over previous
//
#include <hip/hip_runtime.h>

// Local cost-volume correlation, fp32 vector path, DPP window sharing.
// out[b, dy*9+dx, h, w] = (1/256) sum_c in1[b,c,h,w] * in2[b,c,h+dy-4,w+dx-4]
//
// R8 design (from R7 post-mortem: ILP refuted as primary lever — doubling
// loads-in-flight gave 200->188 us, VALUBusy stuck 40%. Bottleneck is TLP:
// 3456 waves = 3.375/SIMD can't cover ~900cy L3/HBM load latency):
//  - SPLIT-K WITHIN BLOCK: 512-thread blocks, 8 waves. Waves 0-3 accumulate
//    channels 0..127, waves 4-7 channels 128..255 (identical R4 core, 44
//    VGPR, zero scratch). Wave count doubles: 6912 -> 6.75/SIMD; coverage
//    6.75 x ~208cy compute/wait ~= 1400cy > 900cy HBM-miss latency.
//  - one-shot LDS reduce: high half writes acc (256 x 37 floats, stride-37
//    padded -> 2 lanes/bank = conflict-free), low half adds + does the
//    proven branch-free OOB-zeroing epilogue. No extra HBM traffic, no
//    atomics, deterministic fp32 order.
//  - NO ping-pong staging (R5-R7 lesson: register pressure near the 128
//    cap triggers pathological scratch streaming; TLP now does the hiding).

#define CH 256
#define HALFC 128
#define HH 96
#define WW 128
#define CS (HH * WW)

__device__ __forceinline__ float wshr1(float x) {  // lane i <- lane i-1
  union { float f; int i; } u, o;
  u.f = x;
  o.i = __builtin_amdgcn_update_dpp(0, u.i, 0x138, 0xF, 0xF, true);
  return o.f;
}
__device__ __forceinline__ float wshl1(float x) {  // lane i <- lane i+1
  union { float f; int i; } u, o;
  u.f = x;
  o.i = __builtin_amdgcn_update_dpp(0, u.i, 0x130, 0xF, 0xF, true);
  return o.f;
}

__global__ __launch_bounds__(512, 4) void corr_split(
    const float* __restrict__ in1, const float* __restrict__ in2,
    float* __restrict__ out)
{
  // ---- block decode, XCD-swizzled: tile's 9 dy-blocks share blockIdx%8 ----
  const int j    = blockIdx.x;          // grid = 864
  const int xcd  = j & 7;
  const int s    = j >> 3;              // 0..107
  const int dy   = s % 9;
  const int tq   = s / 9;               // 0..11
  const int tile = tq * 8 + xcd;        // 0..95
  const int band = tile % 12;
  const int b    = tile / 12;
  const int dyo  = dy - 4;

  // ---- thread decode: 2 ch-halves x 4 waves x (2 rows x 32 groups) ----
  const int tid  = threadIdx.x;
  const int half = tid >> 8;                // channel half: 0 or 1
  const int t    = tid & 255;
  const int wv   = t >> 6;
  const int lane = t & 63;
  const int r    = lane >> 5;
  const int g    = lane & 31;
  const int h    = band * 8 + wv * 2 + r;   // 0..95, always valid
  const int px   = g << 2;                  // 0..124
  const int r2   = h + dyo;                 // in2 row, may be OOB
  const bool rowok = (unsigned)r2 < (unsigned)HH;
  const int r2c  = r2 < 0 ? 0 : (r2 > HH - 1 ? HH - 1 : r2);

  const float* __restrict__ p1 =
      in1 + (((size_t)b * CH + half * HALFC) * HH + h)   * WW + px;
  const float* __restrict__ p2 =
      in2 + (((size_t)b * CH + half * HALFC) * HH + r2c) * WW + px;

  float acc[4][9];
#pragma unroll
  for (int p = 0; p < 4; ++p)
#pragma unroll
    for (int d = 0; d < 9; ++d) acc[p][d] = 0.f;

  // ---- channel loop: 128 channels per half (R4-proven core) ----
#pragma unroll 2
  for (int c = 0; c < HALFC; ++c) {
    float4 a4 = *(const float4*)p1;  p1 += CS;
    float4 m4 = *(const float4*)p2;  p2 += CS;

    // window w[0..11] = in2 cols px-4 .. px+7 (same row), via DPP neighbors
    float w[12];
    w[0] = wshr1(m4.x); w[1] = wshr1(m4.y); w[2] = wshr1(m4.z); w[3] = wshr1(m4.w);
    w[4] = m4.x; w[5] = m4.y; w[6] = m4.z; w[7] = m4.w;
    w[8] = wshl1(m4.x); w[9] = wshl1(m4.y); w[10] = wshl1(m4.z); w[11] = wshl1(m4.w);

    const float av[4] = {a4.x, a4.y, a4.z, a4.w};
#pragma unroll
    for (int p = 0; p < 4; ++p)
#pragma unroll
      for (int d = 0; d < 9; ++d)
        acc[p][d] = fmaf(av[p], w[p + d], acc[p][d]);
  }

  // ---- cross-half reduce via LDS (stride 37: 5t+idx mod 32 -> 2/bank) ----
  __shared__ float red[256][37];
  if (half) {
#pragma unroll
    for (int p = 0; p < 4; ++p)
#pragma unroll
      for (int d = 0; d < 9; ++d) red[t][p * 9 + d] = acc[p][d];
  }
  __syncthreads();

  if (!half) {
#pragma unroll
    for (int p = 0; p < 4; ++p)
#pragma unroll
      for (int d = 0; d < 9; ++d) acc[p][d] += red[t][p * 9 + d];

    // ---- epilogue: zero OOB (row+col), scale, float4 store ----
    const float sc = 1.0f / (float)CH;
    float* po = out + (((size_t)b * 81 + dy * 9) * HH + h) * WW + px;
#pragma unroll
    for (int d = 0; d < 9; ++d) {
      float v[4];
#pragma unroll
      for (int p = 0; p < 4; ++p) {
        const int col2 = px + p + d - 4;                     // in2 column
        const bool ok  = rowok && ((unsigned)col2 < (unsigned)WW);
        v[p] = ok ? acc[p][d] * sc : 0.f;
      }
      *(float4*)po = make_float4(v[0], v[1], v[2], v[3]);
      po += (size_t)CS;  // next (dy,dx) plane
    }
  }
}

extern "C" void kernel_launch(void* const* d_in, const int* in_sizes, int n_in,
                              void* d_out, int out_size, void* d_ws, size_t ws_size,
                              hipStream_t stream) {
  const float* in1 = (const float*)d_in[0];
  const float* in2 = (const float*)d_in[1];
  float* out = (float*)d_out;
  hipLaunchKernelGGL(corr_split, dim3(864), dim3(512), 0, stream, in1, in2, out);
}

// Round 6
// 299.928 us; speedup vs baseline: 2.2870x; 1.0073x over previous
//
#include <hip/hip_runtime.h>

// Local cost-volume correlation, fp32 vector path, DPP window sharing.
// out[b, dy*9+dx, h, w] = (1/256) sum_c in1[b,c,h,w] * in2[b,c,h+dy-4,w+dx-4]
//
// R9 design (from R8 post-mortem: duration scales EXACTLY with 1/occupancy
// — purely residency-limited. R8's 37.9 KB LDS capped residency at ~1.45
// blocks/CU (observed 36% occ), consistent with a ~64 KB schedulable LDS
// pool, not the 160 KiB spec. Fix: shrink LDS below any pool hypothesis):
//  - identical split-K structure to R8: 512 threads = 8 waves; waves 0-3
//    accumulate channels 0..127, waves 4-7 channels 128..255 (R4-proven
//    core: 44 VGPR, zero scratch, DPP window, unroll 2)
//  - CHUNKED cross-half reduce: 4 rounds x 9 floats through red[256][11]
//    = 11.3 KB LDS (was 37.9 KB). Stride 11 coprime with 32 banks ->
//    2 lanes/bank = conflict-free. 8 barriers ~= noise vs channel loop.
//  - >=5 blocks/CU now fit even under a 64 KB pool -> residency should
//    recover to the grid limit (~2.7 blocks/CU, ~21 waves/CU).

#define CH 256
#define HALFC 128
#define HH 96
#define WW 128
#define CS (HH * WW)

__device__ __forceinline__ float wshr1(float x) {  // lane i <- lane i-1
  union { float f; int i; } u, o;
  u.f = x;
  o.i = __builtin_amdgcn_update_dpp(0, u.i, 0x138, 0xF, 0xF, true);
  return o.f;
}
__device__ __forceinline__ float wshl1(float x) {  // lane i <- lane i+1
  union { float f; int i; } u, o;
  u.f = x;
  o.i = __builtin_amdgcn_update_dpp(0, u.i, 0x130, 0xF, 0xF, true);
  return o.f;
}

__global__ __launch_bounds__(512, 4) void corr_split(
    const float* __restrict__ in1, const float* __restrict__ in2,
    float* __restrict__ out)
{
  // ---- block decode, XCD-swizzled: tile's 9 dy-blocks share blockIdx%8 ----
  const int j    = blockIdx.x;          // grid = 864
  const int xcd  = j & 7;
  const int s    = j >> 3;              // 0..107
  const int dy   = s % 9;
  const int tq   = s / 9;               // 0..11
  const int tile = tq * 8 + xcd;        // 0..95
  const int band = tile % 12;
  const int b    = tile / 12;
  const int dyo  = dy - 4;

  // ---- thread decode: 2 ch-halves x 4 waves x (2 rows x 32 groups) ----
  const int tid  = threadIdx.x;
  const int half = tid >> 8;                // channel half: 0 or 1
  const int t    = tid & 255;
  const int wv   = t >> 6;
  const int lane = t & 63;
  const int r    = lane >> 5;
  const int g    = lane & 31;
  const int h    = band * 8 + wv * 2 + r;   // 0..95, always valid
  const int px   = g << 2;                  // 0..124
  const int r2   = h + dyo;                 // in2 row, may be OOB
  const bool rowok = (unsigned)r2 < (unsigned)HH;
  const int r2c  = r2 < 0 ? 0 : (r2 > HH - 1 ? HH - 1 : r2);

  const float* __restrict__ p1 =
      in1 + (((size_t)b * CH + half * HALFC) * HH + h)   * WW + px;
  const float* __restrict__ p2 =
      in2 + (((size_t)b * CH + half * HALFC) * HH + r2c) * WW + px;

  float acc[4][9];
#pragma unroll
  for (int p = 0; p < 4; ++p)
#pragma unroll
    for (int d = 0; d < 9; ++d) acc[p][d] = 0.f;

  // ---- channel loop: 128 channels per half (R4-proven core) ----
#pragma unroll 2
  for (int c = 0; c < HALFC; ++c) {
    float4 a4 = *(const float4*)p1;  p1 += CS;
    float4 m4 = *(const float4*)p2;  p2 += CS;

    // window w[0..11] = in2 cols px-4 .. px+7 (same row), via DPP neighbors
    float w[12];
    w[0] = wshr1(m4.x); w[1] = wshr1(m4.y); w[2] = wshr1(m4.z); w[3] = wshr1(m4.w);
    w[4] = m4.x; w[5] = m4.y; w[6] = m4.z; w[7] = m4.w;
    w[8] = wshl1(m4.x); w[9] = wshl1(m4.y); w[10] = wshl1(m4.z); w[11] = wshl1(m4.w);

    const float av[4] = {a4.x, a4.y, a4.z, a4.w};
#pragma unroll
    for (int p = 0; p < 4; ++p)
#pragma unroll
      for (int d = 0; d < 9; ++d)
        acc[p][d] = fmaf(av[p], w[p + d], acc[p][d]);
  }

  // ---- chunked cross-half reduce: 4 rounds x 9 floats, 11.3 KB LDS ----
  // stride 11 coprime with 32 banks: lanes t..t+63 -> 2/bank, conflict-free
  __shared__ float red[256][11];
#pragma unroll
  for (int pp = 0; pp < 4; ++pp) {
    if (half) {
#pragma unroll
      for (int d = 0; d < 9; ++d) red[t][d] = acc[pp][d];
    }
    __syncthreads();
    if (!half) {
#pragma unroll
      for (int d = 0; d < 9; ++d) acc[pp][d] += red[t][d];
    }
    __syncthreads();   // WAR guard before next round's writes
  }

  if (!half) {
    // ---- epilogue: zero OOB (row+col), scale, float4 store ----
    const float sc = 1.0f / (float)CH;
    float* po = out + (((size_t)b * 81 + dy * 9) * HH + h) * WW + px;
#pragma unroll
    for (int d = 0; d < 9; ++d) {
      float v[4];
#pragma unroll
      for (int p = 0; p < 4; ++p) {
        const int col2 = px + p + d - 4;                     // in2 column
        const bool ok  = rowok && ((unsigned)col2 < (unsigned)WW);
        v[p] = ok ? acc[p][d] * sc : 0.f;
      }
      *(float4*)po = make_float4(v[0], v[1], v[2], v[3]);
      po += (size_t)CS;  // next (dy,dx) plane
    }
  }
}

extern "C" void kernel_launch(void* const* d_in, const int* in_sizes, int n_in,
                              void* d_out, int out_size, void* d_ws, size_t ws_size,
                              hipStream_t stream) {
  const float* in1 = (const float*)d_in[0];
  const float* in2 = (const float*)d_in[1];
  float* out = (float*)d_out;
  hipLaunchKernelGGL(corr_split, dim3(864), dim3(512), 0, stream, in1, in2, out);
}